// Round 1
// baseline (37.675 us; speedup 1.0000x reference)
//
#include <hip/hip_runtime.h>
#include <math.h>

// Tropical (min-plus) matmul: out[b, j] = min_i (X[b, i] + W[j, i])
// X: [B=1024, IN=512] fp32 row-major
// W: [OUT=512, IN=512] fp32 row-major  (note: both have IN contiguous -> A*B^T shape)
// out: [B, OUT] fp32

#define B_DIM   1024
#define IN_DIM  512
#define OUT_DIM 512

constexpr int BM = 32;   // rows of X per block
constexpr int BN = 64;   // rows of W (output cols) per block
constexpr int BK = 32;   // k-tile
constexpr int TM = 2;    // outputs per thread, m
constexpr int TN = 4;    // outputs per thread, n
// threads = (BM/TM) * (BN/TN) = 16 * 16 = 256

constexpr int XS_STRIDE = BM + 2;  // 34: even -> float2-aligned reads, 2-way bank alias (free)
constexpr int WS_STRIDE = BN + 4;  // 68: %4==0 -> float4-aligned reads

__global__ __launch_bounds__(256)
void MinPlus_70832600646269_kernel(const float* __restrict__ X,
                                   const float* __restrict__ W,
                                   float* __restrict__ out)
{
    __shared__ float Xs[BK][XS_STRIDE];  // Xs[k][m]  (transposed)
    __shared__ float Ws[BK][WS_STRIDE];  // Ws[k][n]  (transposed)

    const int tid = threadIdx.x;
    const int n0  = blockIdx.x * BN;
    const int m0  = blockIdx.y * BM;

    // compute-phase coords
    const int tn = (tid & 15) * TN;   // 0..60, step 4
    const int tm = (tid >> 4) * TM;   // 0..30, step 2

    // load-phase coords: each thread loads one float4 of X, two float4 of W
    const int lm = tid >> 3;          // 0..31
    const int lk = (tid & 7) * 4;     // 0..28

    float acc[TM][TN];
#pragma unroll
    for (int i = 0; i < TM; ++i)
#pragma unroll
        for (int j = 0; j < TN; ++j)
            acc[i][j] = INFINITY;

    for (int k0 = 0; k0 < IN_DIM; k0 += BK) {
        // ---- global -> regs (coalesced float4) ----
        const float4 xv  = *reinterpret_cast<const float4*>(&X[(m0 + lm) * IN_DIM + k0 + lk]);
        const float4 wv0 = *reinterpret_cast<const float4*>(&W[(n0 + lm) * IN_DIM + k0 + lk]);
        const float4 wv1 = *reinterpret_cast<const float4*>(&W[(n0 + lm + 32) * IN_DIM + k0 + lk]);

        __syncthreads();  // previous iteration's compute must finish before we overwrite LDS

        // ---- regs -> LDS, transposed ----
        Xs[lk + 0][lm] = xv.x;
        Xs[lk + 1][lm] = xv.y;
        Xs[lk + 2][lm] = xv.z;
        Xs[lk + 3][lm] = xv.w;

        Ws[lk + 0][lm] = wv0.x;
        Ws[lk + 1][lm] = wv0.y;
        Ws[lk + 2][lm] = wv0.z;
        Ws[lk + 3][lm] = wv0.w;
        Ws[lk + 0][lm + 32] = wv1.x;
        Ws[lk + 1][lm + 32] = wv1.y;
        Ws[lk + 2][lm + 32] = wv1.z;
        Ws[lk + 3][lm + 32] = wv1.w;

        __syncthreads();

        // ---- compute: k unrolled by 2, fminf-chain to invite v_min3_f32 ----
#pragma unroll
        for (int k = 0; k < BK; k += 2) {
            const float2 xa = *reinterpret_cast<const float2*>(&Xs[k][tm]);
            const float2 xb = *reinterpret_cast<const float2*>(&Xs[k + 1][tm]);
            const float4 wa = *reinterpret_cast<const float4*>(&Ws[k][tn]);
            const float4 wb = *reinterpret_cast<const float4*>(&Ws[k + 1][tn]);

            const float w0[TN] = {wa.x, wa.y, wa.z, wa.w};
            const float w1[TN] = {wb.x, wb.y, wb.z, wb.w};

#pragma unroll
            for (int j = 0; j < TN; ++j) {
                acc[0][j] = fminf(fminf(acc[0][j], xa.x + w0[j]), xb.x + w1[j]);
                acc[1][j] = fminf(fminf(acc[1][j], xa.y + w0[j]), xb.y + w1[j]);
            }
        }
    }

    // ---- epilogue: coalesced float4 stores ----
#pragma unroll
    for (int i = 0; i < TM; ++i) {
        const float4 o = make_float4(acc[i][0], acc[i][1], acc[i][2], acc[i][3]);
        *reinterpret_cast<float4*>(&out[(m0 + tm + i) * OUT_DIM + n0 + tn]) = o;
    }
}

extern "C" void kernel_launch(void* const* d_in, const int* in_sizes, int n_in,
                              void* d_out, int out_size, void* d_ws, size_t ws_size,
                              hipStream_t stream) {
    const float* X = (const float*)d_in[0];
    const float* W = (const float*)d_in[1];
    float* out = (float*)d_out;

    dim3 grid(OUT_DIM / BN, B_DIM / BM);  // (8, 32) = 256 blocks
    dim3 block(256);
    MinPlus_70832600646269_kernel<<<grid, block, 0, stream>>>(X, W, out);
}